// Round 5
// baseline (216.562 us; speedup 1.0000x reference)
//
#include <hip/hip_runtime.h>

typedef _Float16 f16x8 __attribute__((ext_vector_type(8)));
typedef _Float16 f16x4t __attribute__((ext_vector_type(4)));
typedef __fp16 h16x2 __attribute__((ext_vector_type(2)));
typedef float f32x4 __attribute__((ext_vector_type(4)));
typedef float f32x16 __attribute__((ext_vector_type(16)));

#define L_SZ 4096

__device__ __forceinline__ unsigned short f2h(float f) {
    _Float16 h = (_Float16)f;
    return __builtin_bit_cast(unsigned short, h);
}
__device__ __forceinline__ unsigned int pk2(float a, float b) {
    h16x2 p = __builtin_amdgcn_cvt_pkrtz(a, b);
    return __builtin_bit_cast(unsigned int, p);
}
// load 8 consecutive fp32, return as f16x8 fragment
__device__ __forceinline__ f16x8 ld8f(const float* __restrict__ p) {
    float4 a = *(const float4*)p;
    float4 b = *(const float4*)(p + 4);
    uint4 u;
    u.x = pk2(a.x, a.y); u.y = pk2(a.z, a.w);
    u.z = pk2(b.x, b.y); u.w = pk2(b.z, b.w);
    return __builtin_bit_cast(f16x8, u);
}

// LDS slot for 64-row x 8-chunk (16B) K/V tiles: chunk-major, row^chunk xor.
// Frag reads per (chunk,half) are contiguous 512B (conflict-free); writes ~2-way.
#define SLOT(row, ci) ((((ci) * 64) + ((row) & 32) + (((row) & 31) ^ (ci))) * 8)

// ---------------- K1: QKV projection (proj-split, inline weight cvt) -------
// Grid 768 = proj(3) x b(4) x lt(64). x:(b,128,L) fp32.
// Out: Qp,Kp:(bh,l,64) f16 (Q scaled log2e/8), Vp:(b,c,L) f16.
__global__ __launch_bounds__(256) void qkv_kernel(
    const float* __restrict__ x,
    const float* __restrict__ wq, const float* __restrict__ bq,
    const float* __restrict__ wk, const float* __restrict__ bk,
    const float* __restrict__ wv, const float* __restrict__ bv,
    unsigned short* __restrict__ Qp, unsigned short* __restrict__ Kp,
    unsigned short* __restrict__ Vp)
{
    int blk = blockIdx.x;
    int proj = blk >> 8;               // 0=Q 1=K 2=V
    int rem = blk & 255;
    int bidx = rem >> 6;
    int l0 = (rem & 63) * 64;
    int tid = threadIdx.x;
    int wave = tid >> 6, lane = tid & 63;
    int c = lane & 15, qd = lane >> 4;

    const float* W   = (proj == 0) ? wq : (proj == 1 ? wk : wv);
    const float* bia = (proj == 0) ? bq : (proj == 1 ? bk : bv);

    __shared__ __align__(16) unsigned short Sh[8448];  // Xs: 64x128 (8192) / Vt: 128x66

    // ---- stage x tile into Xs [l][i], chunk ci at ci^(l&15)
    unsigned short* Xs = Sh;
    #pragma unroll
    for (int it = 0; it < 8; ++it) {
        int i  = (tid >> 4) + 16 * it;
        int l4 = (tid & 15) * 4;
        const float4 v = *(const float4*)&x[(bidx * 128 + i) * L_SZ + l0 + l4];
        float vv[4] = {v.x, v.y, v.z, v.w};
        int ci = i >> 3;
        #pragma unroll
        for (int u = 0; u < 4; ++u) {
            int l = l4 + u;
            Xs[l * 128 + ((ci ^ (l & 15)) * 8) + (i & 7)] = f2h(vv[u]);
        }
    }
    __syncthreads();

    f16x8 afrag[4];
    #pragma unroll
    for (int kc = 0; kc < 4; ++kc) {
        int l = wave * 16 + c;
        int ci = kc * 4 + qd;
        afrag[kc] = *(const f16x8*)&Xs[l * 128 + ((ci ^ (l & 15)) * 8)];
    }
    __syncthreads();   // Xs reads done before Vt overwrites Sh

    f32x4 acc[8];
    #pragma unroll
    for (int nt = 0; nt < 8; ++nt) acc[nt] = (f32x4){0.f, 0.f, 0.f, 0.f};

    #pragma unroll
    for (int kc = 0; kc < 4; ++kc) {
        #pragma unroll
        for (int nt = 0; nt < 8; ++nt) {
            int o = nt * 16 + c;   // 0..127
            f16x8 bfrag = ld8f(&W[o * 128 + kc * 32 + qd * 8]);
            acc[nt] = __builtin_amdgcn_mfma_f32_16x16x32_f16(afrag[kc], bfrag, acc[nt], 0, 0, 0);
        }
    }

    const float s_q = 0.18033688011f;  // log2(e)/8
    if (proj < 2) {
        unsigned short* dst = (proj == 0) ? Qp : Kp;
        #pragma unroll
        for (int nt = 0; nt < 8; ++nt) {
            int o = nt * 16 + c;
            int h = o >> 6, d = o & 63;
            float bo = bia[o];
            #pragma unroll
            for (int r = 0; r < 4; ++r) {
                int l = l0 + wave * 16 + qd * 4 + r;
                float val = acc[nt][r] + bo;
                if (proj == 0) val *= s_q;
                dst[((bidx * 2 + h) * L_SZ + l) * 64 + d] = f2h(val);
            }
        }
    } else {
        unsigned short* Vt = Sh;   // [o][66]
        #pragma unroll
        for (int nt = 0; nt < 8; ++nt) {
            int o = nt * 16 + c;
            float bo = bia[o];
            #pragma unroll
            for (int r = 0; r < 4; ++r) {
                int ll = wave * 16 + qd * 4 + r;
                Vt[o * 66 + ll] = f2h(acc[nt][r] + bo);
            }
        }
        __syncthreads();
        // coalesced store: 128 rows x 64 tokens, 64B per thread
        int row = tid >> 1;
        int seg = (tid & 1) * 32;
        #pragma unroll
        for (int k = 0; k < 4; ++k) {
            uint4 a;
            a.x = *(unsigned int*)&Vt[row * 66 + seg + k * 8 + 0];
            a.y = *(unsigned int*)&Vt[row * 66 + seg + k * 8 + 2];
            a.z = *(unsigned int*)&Vt[row * 66 + seg + k * 8 + 4];
            a.w = *(unsigned int*)&Vt[row * 66 + seg + k * 8 + 6];
            *(uint4*)&Vp[(size_t)(bidx * 128 + row) * L_SZ + l0 + seg + k * 8] = a;
        }
    }
}

// ---------------- K2: flash attention (32KB LDS, all-resident, 2-barrier) --
// Grid 1024 = sp(4) x bh(8) x ltile(32). 4 waves x 32 q-rows.
// Opart f16 [sp][bh][d][l] unnormalized; Mpart/Lpart f32 [sp][bh][l].
__global__ __launch_bounds__(256, 4) void attn_kernel(
    const unsigned short* __restrict__ Qp, const unsigned short* __restrict__ Kp,
    const unsigned short* __restrict__ Vp,
    unsigned short* __restrict__ Opart, float* __restrict__ Mpart, float* __restrict__ Lpart)
{
    int blk = blockIdx.x;
    int lt = blk & 31;
    int bh = (blk >> 5) & 7;
    int sp = blk >> 8;
    int l0 = lt * 128;
    int tid = threadIdx.x;
    int wave = tid >> 6, lane = tid & 63;
    int ln = lane & 31, hi = lane >> 5;
    int b = bh >> 1, h = bh & 1;

    __shared__ __align__(16) unsigned short Ks[4096];
    __shared__ __align__(16) unsigned short Vs[4096];
    __shared__ __align__(16) unsigned short Ps[4][2048];

    const unsigned short* Qb = Qp + (size_t)bh * L_SZ * 64;
    const unsigned short* Kb = Kp + (size_t)bh * L_SZ * 64;
    const unsigned short* Vb = Vp + ((size_t)b * 128 + h * 64) * L_SZ;

    int lq = l0 + wave * 32 + ln;
    f16x8 qf[4];   // B-operand: n = q-row ln, k chunks
    #pragma unroll
    for (int kc = 0; kc < 4; ++kc)
        qf[kc] = *(const f16x8*)&Qb[(size_t)lq * 64 + kc * 16 + hi * 8];

    float m_st = -1e30f, lsum = 0.f;
    f32x16 acc0 = {}, acc1 = {};

    int urow = tid >> 3, uci = tid & 7;
    int mglob = sp * 1024;

    uint4 kreg[2], vreg[2];
    #pragma unroll
    for (int j = 0; j < 2; ++j) {
        int row = urow + j * 32;
        kreg[j] = *(const uint4*)&Kb[(size_t)(mglob + row) * 64 + uci * 8];
        vreg[j] = *(const uint4*)&Vb[(size_t)row * L_SZ + mglob + uci * 8];
    }

    for (int it = 0; it < 16; ++it) {
        __syncthreads();                   // prior iter's K/V frag reads done
        #pragma unroll
        for (int j = 0; j < 2; ++j) {
            int row = urow + j * 32;
            *(uint4*)&Ks[SLOT(row, uci)] = kreg[j];
            *(uint4*)&Vs[SLOT(row, uci)] = vreg[j];
        }
        if (it < 15) {                     // prefetch next tile; in flight thru compute
            int m0 = mglob + (it + 1) * 64;
            #pragma unroll
            for (int j = 0; j < 2; ++j) {
                int row = urow + j * 32;
                kreg[j] = *(const uint4*)&Kb[(size_t)(m0 + row) * 64 + uci * 8];
                vreg[j] = *(const uint4*)&Vb[(size_t)row * L_SZ + m0 + uci * 8];
            }
        }
        __syncthreads();                   // staging visible

        // S^T = K . Q^T
        f32x16 s0 = {}, s1 = {};
        #pragma unroll
        for (int kc = 0; kc < 4; ++kc) {
            int cd = kc * 2 + hi;
            f16x8 k0 = *(const f16x8*)&Ks[SLOT(ln, cd)];
            f16x8 k1 = *(const f16x8*)&Ks[SLOT(32 + ln, cd)];
            s0 = __builtin_amdgcn_mfma_f32_32x32x16_f16(k0, qf[kc], s0, 0, 0, 0);
            s1 = __builtin_amdgcn_mfma_f32_32x32x16_f16(k1, qf[kc], s1, 0, 0, 0);
        }

        // online softmax (base-2; log2e folded into Q)
        float mx = s0[0];
        #pragma unroll
        for (int r = 1; r < 16; ++r) mx = fmaxf(mx, s0[r]);
        #pragma unroll
        for (int r = 0; r < 16; ++r) mx = fmaxf(mx, s1[r]);
        mx = fmaxf(mx, __shfl_xor(mx, 32));
        if (__any(mx > m_st)) {            // wave-uniform: skip rescale when stale max holds
            float mnew = fmaxf(m_st, mx);
            float alpha = exp2f(m_st - mnew);
            m_st = mnew;
            lsum *= alpha;
            #pragma unroll
            for (int r = 0; r < 16; ++r) { acc0[r] *= alpha; acc1[r] *= alpha; }
        }
        float rsum = 0.f;
        #pragma unroll
        for (int r = 0; r < 16; ++r) { float p = exp2f(s0[r] - m_st); s0[r] = p; rsum += p; }
        #pragma unroll
        for (int r = 0; r < 16; ++r) { float p = exp2f(s1[r] - m_st); s1[r] = p; rsum += p; }
        lsum += rsum;

        // P -> per-wave LDS
        #pragma unroll
        for (int g = 0; g < 4; ++g) {
            uint2 w0;
            w0.x = pk2(s0[g * 4 + 0], s0[g * 4 + 1]);
            w0.y = pk2(s0[g * 4 + 2], s0[g * 4 + 3]);
            *(uint2*)&Ps[wave][(g * 32 + (ln ^ g)) * 8 + hi * 4] = w0;
            int g2 = 4 + g;
            uint2 w1;
            w1.x = pk2(s1[g * 4 + 0], s1[g * 4 + 1]);
            w1.y = pk2(s1[g * 4 + 2], s1[g * 4 + 3]);
            *(uint2*)&Ps[wave][(g2 * 32 + (ln ^ g2)) * 8 + hi * 4] = w1;
        }

        // O^T += V . P^T  (per-wave P; lgkmcnt orders write->read)
        #pragma unroll
        for (int kc = 0; kc < 4; ++kc) {
            int cd = kc * 2 + hi;
            f16x8 pf = *(const f16x8*)&Ps[wave][(cd * 32 + (ln ^ cd)) * 8];
            f16x8 v0 = *(const f16x8*)&Vs[SLOT(ln, cd)];
            f16x8 v1 = *(const f16x8*)&Vs[SLOT(32 + ln, cd)];
            acc0 = __builtin_amdgcn_mfma_f32_32x32x16_f16(v0, pf, acc0, 0, 0, 0);
            acc1 = __builtin_amdgcn_mfma_f32_32x32x16_f16(v1, pf, acc1, 0, 0, 0);
        }
    }

    float l_tot = lsum + __shfl_xor(lsum, 32);
    unsigned short* Ow = Opart + (size_t)(sp * 8 + bh) * 64 * 4096;
    #pragma unroll
    for (int r = 0; r < 16; ++r) {
        int d0 = (r & 3) + 8 * (r >> 2) + 4 * hi;
        Ow[(size_t)d0 * 4096 + lq] = f2h(acc0[r]);
        Ow[(size_t)(32 + d0) * 4096 + lq] = f2h(acc1[r]);
    }
    if (hi == 0) {
        Mpart[(sp * 8 + bh) * 4096 + lq] = m_st;
        Lpart[(sp * 8 + bh) * 4096 + lq] = l_tot;
    }
}

// ---------------- K2b: per-(bh,l) combine scales -> f16x4 ----------------
__global__ __launch_bounds__(256) void scale_kernel(
    const float* __restrict__ Mp, const float* __restrict__ Lp,
    unsigned short* __restrict__ Scl)
{
    int t = blockIdx.x * 256 + threadIdx.x;   // 0..32767 = bh*4096 + l
    float m[4], l[4];
    #pragma unroll
    for (int s = 0; s < 4; ++s) { m[s] = Mp[s * 32768 + t]; l[s] = Lp[s * 32768 + t]; }
    float mx = fmaxf(fmaxf(m[0], m[1]), fmaxf(m[2], m[3]));
    float a[4], den = 0.f;
    #pragma unroll
    for (int s = 0; s < 4; ++s) { a[s] = exp2f(m[s] - mx); den += a[s] * l[s]; }
    float inv = 1.0f / den;
    uint2 sc;
    sc.x = pk2(a[0] * inv, a[1] * inv);
    sc.y = pk2(a[2] * inv, a[3] * inv);
    *(uint2*)&Scl[t * 4] = sc;
}

// ---------------- K3: combine + fc + BN + PReLU (no LDS) ----------------
// Grid 512 = b(4) x ch(128), block 128 (2 waves x 16 token-rows), out fp32.
__global__ __launch_bounds__(128) void fc_kernel(
    const unsigned short* __restrict__ Opart, const unsigned short* __restrict__ Scl,
    const float* __restrict__ fcw_f, const float* __restrict__ fc_b,
    const float* __restrict__ bn_g, const float* __restrict__ bn_b,
    const float* __restrict__ bn_m, const float* __restrict__ bn_v,
    const float* __restrict__ prelu_a, float* __restrict__ out)
{
    int blk = blockIdx.x;
    int ch = blk & 127;
    int bh = (blk >> 7) * 2 + (ch >> 6);
    int d = ch & 63;
    int tid = threadIdx.x;
    int wave = tid >> 6, lane = tid & 63;
    int c = lane & 15, qd = lane >> 4;
    int hh = wave * 16 + c;                 // token h-index of A-row

    size_t obase = (size_t)bh * 262144 + (size_t)d * 4096 + hh * 128;
    int sbase = (bh << 12) + hh * 128;

    f16x8 af[4];
    #pragma unroll
    for (int kc = 0; kc < 4; ++kc) {
        int w0 = kc * 32 + qd * 8;
        f16x8 ov[4];
        #pragma unroll
        for (int s = 0; s < 4; ++s)
            ov[s] = *(const f16x8*)&Opart[(size_t)s * 2097152 + obase + w0];
        #pragma unroll
        for (int j = 0; j < 8; ++j) {
            f16x4t sc = *(const f16x4t*)&Scl[(sbase + w0 + j) * 4];
            float v = (float)ov[0][j] * (float)sc[0] + (float)ov[1][j] * (float)sc[1]
                    + (float)ov[2][j] * (float)sc[2] + (float)ov[3][j] * (float)sc[3];
            af[kc][j] = (_Float16)v;
        }
    }

    f32x4 acc[8];
    #pragma unroll
    for (int nt = 0; nt < 8; ++nt) acc[nt] = (f32x4){0.f, 0.f, 0.f, 0.f};
    #pragma unroll
    for (int kc = 0; kc < 4; ++kc) {
        #pragma unroll
        for (int nt = 0; nt < 8; ++nt) {
            f16x8 bf = ld8f(&fcw_f[(nt * 16 + c) * 128 + kc * 32 + qd * 8]);
            acc[nt] = __builtin_amdgcn_mfma_f32_16x16x32_f16(af[kc], bf, acc[nt], 0, 0, 0);
        }
    }

    float pa = prelu_a[0];
    float g  = bn_g[ch] * rsqrtf(bn_v[ch] + 1e-5f);
    float mn = bn_m[ch], bt = bn_b[ch];
    int rbase = blk * 32 + wave * 16;
    #pragma unroll
    for (int r = 0; r < 4; ++r) {
        int orow = rbase + qd * 4 + r;
        #pragma unroll
        for (int nt = 0; nt < 8; ++nt) {
            int o = nt * 16 + c;
            float y = (acc[nt][r] + fc_b[o] - mn) * g + bt;
            y = y > 0.f ? y : pa * y;
            out[(size_t)orow * 128 + o] = y;
        }
    }
}

extern "C" void kernel_launch(void* const* d_in, const int* in_sizes, int n_in,
                              void* d_out, int out_size, void* d_ws, size_t ws_size,
                              hipStream_t stream) {
    const float* x     = (const float*)d_in[0];
    const float* wq    = (const float*)d_in[1];
    const float* bq    = (const float*)d_in[2];
    const float* wk    = (const float*)d_in[3];
    const float* bk    = (const float*)d_in[4];
    const float* wv    = (const float*)d_in[5];
    const float* bv    = (const float*)d_in[6];
    const float* fcw_f = (const float*)d_in[7];
    const float* fcb   = (const float*)d_in[8];
    const float* bn_g  = (const float*)d_in[9];
    const float* bn_b  = (const float*)d_in[10];
    const float* bn_m  = (const float*)d_in[11];
    const float* bn_v  = (const float*)d_in[12];
    const float* pa    = (const float*)d_in[13];
    float* out = (float*)d_out;

    unsigned short* Qp  = (unsigned short*)d_ws;
    unsigned short* Kp  = Qp + 8 * L_SZ * 64;
    unsigned short* Vp  = Kp + 8 * L_SZ * 64;
    unsigned short* Opart = Vp + 8 * L_SZ * 64;   // f16, 4*8*64*4096
    float* Mpart = (float*)(Opart + 4 * 8 * 64 * L_SZ);
    float* Lpart = Mpart + 4 * 8 * L_SZ;
    unsigned short* Scl = (unsigned short*)(Lpart + 4 * 8 * L_SZ);  // 32768*4 f16

    hipLaunchKernelGGL(qkv_kernel,   dim3(768),  dim3(256), 0, stream,
                       x, wq, bq, wk, bk, wv, bv, Qp, Kp, Vp);
    hipLaunchKernelGGL(attn_kernel,  dim3(1024), dim3(256), 0, stream,
                       Qp, Kp, Vp, Opart, Mpart, Lpart);
    hipLaunchKernelGGL(scale_kernel, dim3(128),  dim3(256), 0, stream,
                       Mpart, Lpart, Scl);
    hipLaunchKernelGGL(fc_kernel,    dim3(512),  dim3(128), 0, stream,
                       Opart, Scl, fcw_f, fcb, bn_g, bn_b, bn_m, bn_v, pa, out);
}

// Round 8
// 178.537 us; speedup vs baseline: 1.2130x; 1.2130x over previous
//
#include <hip/hip_runtime.h>

typedef _Float16 f16x8 __attribute__((ext_vector_type(8)));
typedef _Float16 f16x4t __attribute__((ext_vector_type(4)));
typedef __fp16 h16x2 __attribute__((ext_vector_type(2)));
typedef float f32x4 __attribute__((ext_vector_type(4)));
typedef float f32x16 __attribute__((ext_vector_type(16)));

#define L_SZ 4096

__device__ __forceinline__ unsigned short f2h(float f) {
    _Float16 h = (_Float16)f;
    return __builtin_bit_cast(unsigned short, h);
}
__device__ __forceinline__ unsigned int pk2(float a, float b) {
    h16x2 p = __builtin_amdgcn_cvt_pkrtz(a, b);
    return __builtin_bit_cast(unsigned int, p);
}

// Round-4 attn LDS slot: 64-row x 8-chunk (16B) K/V tiles, chunk-major, XOR perm.
#define SLOT(row, ci) ((((ci) * 64) + ((row) & 32) + (((row) & 31) ^ (ci))) * 8)

// ---------------- K0: convert weights fp32 -> f16 ----------------
__global__ __launch_bounds__(256) void cvt_kernel(
    const float* __restrict__ wq, const float* __restrict__ wk,
    const float* __restrict__ wv, const float* __restrict__ fcw_f,
    unsigned short* __restrict__ Wc, unsigned short* __restrict__ fcwh)
{
    int t = blockIdx.x * 256 + threadIdx.x;   // 65536
    if (t < 16384)       Wc[t]          = f2h(wq[t]);
    else if (t < 32768)  Wc[t]          = f2h(wk[t - 16384]);
    else if (t < 49152)  Wc[t]          = f2h(wv[t - 32768]);
    else                 fcwh[t - 49152] = f2h(fcw_f[t - 49152]);
}

// ---------------- K1: QKV projection -------------------------------------
// Grid 1536 = proj(3) x b(4) x lt(128 of 32 tokens). Block 256 (4 waves).
// Out: Qp,Kp:(bh,l,64) f16 (Q scaled log2e/8), Vp:(b,c,L) f16.
__global__ __launch_bounds__(256) void qkv_kernel(
    const float* __restrict__ x, const unsigned short* __restrict__ Wc,
    const float* __restrict__ bq, const float* __restrict__ bk, const float* __restrict__ bv,
    unsigned short* __restrict__ Qp, unsigned short* __restrict__ Kp,
    unsigned short* __restrict__ Vp)
{
    int blk = blockIdx.x;
    int proj = blk >> 9;               // 0=Q 1=K 2=V
    int rem = blk & 511;
    int bidx = rem >> 7;
    int l0 = (rem & 127) * 32;
    int tid = threadIdx.x;
    int wave = tid >> 6, lane = tid & 63;
    int c = lane & 15, qd = lane >> 4;

    const float* bia = (proj == 0) ? bq : (proj == 1 ? bk : bv);

    __shared__ __align__(16) unsigned short Sh[5120];  // Xs 4096 / Qt 4352 / Vt 5120

    // stage x tile (32 l x 128 i) -> Xs [l][i] f16, chunk ci at ci^(l&15)
    {
        int i  = tid >> 1;
        int lh = (tid & 1) * 16;
        const float* xs = &x[((size_t)bidx * 128 + i) * L_SZ + l0 + lh];
        float4 v0 = *(const float4*)xs;
        float4 v1 = *(const float4*)(xs + 4);
        float4 v2 = *(const float4*)(xs + 8);
        float4 v3 = *(const float4*)(xs + 12);
        float vv[16] = {v0.x,v0.y,v0.z,v0.w, v1.x,v1.y,v1.z,v1.w,
                        v2.x,v2.y,v2.z,v2.w, v3.x,v3.y,v3.z,v3.w};
        int ci = i >> 3, ij = i & 7;
        #pragma unroll
        for (int t = 0; t < 16; ++t) {
            int l = lh + t;
            Sh[l * 128 + ((ci ^ (l & 15)) * 8) + ij] = f2h(vv[t]);
        }
    }
    __syncthreads();

    f16x8 af[2][4];
    #pragma unroll
    for (int lt2 = 0; lt2 < 2; ++lt2)
        #pragma unroll
        for (int kc = 0; kc < 4; ++kc)
            af[lt2][kc] = *(const f16x8*)&Sh[(lt2 * 16 + c) * 128 + (((kc * 4 + qd) ^ c) * 8)];
    __syncthreads();   // Xs reads done before epilogue overwrites Sh

    f32x4 acc[2][2];
    #pragma unroll
    for (int lt2 = 0; lt2 < 2; ++lt2)
        #pragma unroll
        for (int nt = 0; nt < 2; ++nt) acc[lt2][nt] = (f32x4){0.f,0.f,0.f,0.f};

    const unsigned short* Wp = Wc + proj * 16384;
    #pragma unroll
    for (int kc = 0; kc < 4; ++kc) {
        #pragma unroll
        for (int nt = 0; nt < 2; ++nt) {
            int o = wave * 32 + nt * 16 + c;
            f16x8 bf = *(const f16x8*)&Wp[o * 128 + kc * 32 + qd * 8];
            acc[0][nt] = __builtin_amdgcn_mfma_f32_16x16x32_f16(af[0][kc], bf, acc[0][nt], 0, 0, 0);
            acc[1][nt] = __builtin_amdgcn_mfma_f32_16x16x32_f16(af[1][kc], bf, acc[1][nt], 0, 0, 0);
        }
    }

    const float s_q = 0.18033688011f;  // log2(e)/8
    if (proj < 2) {
        // Qt [l=32][136]
        #pragma unroll
        for (int lt2 = 0; lt2 < 2; ++lt2)
            #pragma unroll
            for (int nt = 0; nt < 2; ++nt) {
                int o = wave * 32 + nt * 16 + c;
                float bo = bia[o];
                #pragma unroll
                for (int r = 0; r < 4; ++r) {
                    float val = acc[lt2][nt][r] + bo;
                    if (proj == 0) val *= s_q;
                    Sh[(lt2 * 16 + qd * 4 + r) * 136 + o] = f2h(val);
                }
            }
        __syncthreads();
        unsigned short* dstp = (proj == 0) ? Qp : Kp;
        int l = tid >> 3, cp = tid & 7;
        int h = cp >> 2;
        uint4 q0 = *(const uint4*)&Sh[l * 136 + cp * 16];
        uint4 q1 = *(const uint4*)&Sh[l * 136 + cp * 16 + 8];
        unsigned short* d0 = &dstp[((size_t)(bidx * 2 + h) * L_SZ + l0 + l) * 64 + ((cp * 16) & 63)];
        *(uint4*)d0 = q0;
        *(uint4*)(d0 + 8) = q1;
    } else {
        // Vt [o=128][40]
        #pragma unroll
        for (int lt2 = 0; lt2 < 2; ++lt2)
            #pragma unroll
            for (int nt = 0; nt < 2; ++nt) {
                int o = wave * 32 + nt * 16 + c;
                float bo = bia[o];
                #pragma unroll
                for (int r = 0; r < 4; ++r)
                    Sh[o * 40 + lt2 * 16 + qd * 4 + r] = f2h(acc[lt2][nt][r] + bo);
            }
        __syncthreads();
        int row = tid >> 1, half = (tid & 1) * 16;
        uint4 a0 = *(const uint4*)&Sh[row * 40 + half];
        uint4 a1 = *(const uint4*)&Sh[row * 40 + half + 8];
        unsigned short* d0 = &Vp[((size_t)(bidx * 128 + row)) * L_SZ + l0 + half];
        *(uint4*)d0 = a0;
        *(uint4*)(d0 + 8) = a1;
    }
}

// ---------------- K2: flash attention (round-4 verbatim) ------------------
// Grid 1024 = sp(4) x bh(8) x ltile(32). 4 waves x 32 q-rows.
// Opart f16 [sp][bh][d][l] unnormalized; Mpart/Lpart f32 [sp][bh][l].
__global__ __launch_bounds__(256, 3) void attn_kernel(
    const unsigned short* __restrict__ Qp, const unsigned short* __restrict__ Kp,
    const unsigned short* __restrict__ Vp,
    unsigned short* __restrict__ Opart, float* __restrict__ Mpart, float* __restrict__ Lpart)
{
    int blk = blockIdx.x;
    int lt = blk & 31;
    int bh = (blk >> 5) & 7;
    int sp = blk >> 8;
    int l0 = lt * 128;
    int tid = threadIdx.x;
    int wave = tid >> 6, lane = tid & 63;
    int ln = lane & 31, hi = lane >> 5;
    int b = bh >> 1, h = bh & 1;

    __shared__ __align__(16) unsigned short Ks[2][4096];
    __shared__ __align__(16) unsigned short Vs[2][4096];
    __shared__ __align__(16) unsigned short Ps[4][2048];

    const unsigned short* Qb = Qp + (size_t)bh * L_SZ * 64;
    const unsigned short* Kb = Kp + (size_t)bh * L_SZ * 64;
    const unsigned short* Vb = Vp + ((size_t)b * 128 + h * 64) * L_SZ;

    int lq = l0 + wave * 32 + ln;
    f16x8 qf[4];   // B-operand: n = q-row ln, k chunks
    #pragma unroll
    for (int kc = 0; kc < 4; ++kc)
        qf[kc] = *(const f16x8*)&Qb[(size_t)lq * 64 + kc * 16 + hi * 8];

    float m_st = -1e30f, lsum = 0.f;
    f32x16 acc0 = {}, acc1 = {};

    int urow = tid >> 3, uci = tid & 7;   // staging assignment (rows 0..31 / +32)
    int mglob = sp * 1024;

    uint4 kreg[2], vreg[2];
    // prologue: tile 0
    #pragma unroll
    for (int j = 0; j < 2; ++j) {
        int row = urow + j * 32;
        kreg[j] = *(const uint4*)&Kb[(size_t)(mglob + row) * 64 + uci * 8];
        vreg[j] = *(const uint4*)&Vb[(size_t)row * L_SZ + mglob + uci * 8];
    }
    #pragma unroll
    for (int j = 0; j < 2; ++j) {
        int row = urow + j * 32;
        *(uint4*)&Ks[0][SLOT(row, uci)] = kreg[j];
        *(uint4*)&Vs[0][SLOT(row, uci)] = vreg[j];
    }

    for (int it = 0; it < 16; ++it) {
        int cur = it & 1;
        __syncthreads();                   // buf[cur] ready for everyone
        if (it < 15) {                     // prefetch next tile to regs
            int m0 = mglob + (it + 1) * 64;
            #pragma unroll
            for (int j = 0; j < 2; ++j) {
                int row = urow + j * 32;
                kreg[j] = *(const uint4*)&Kb[(size_t)(m0 + row) * 64 + uci * 8];
                vreg[j] = *(const uint4*)&Vb[(size_t)row * L_SZ + m0 + uci * 8];
            }
        }

        // S^T = K . Q^T
        f32x16 s0 = {}, s1 = {};
        #pragma unroll
        for (int kc = 0; kc < 4; ++kc) {
            int cd = kc * 2 + hi;
            f16x8 k0 = *(const f16x8*)&Ks[cur][SLOT(ln, cd)];
            f16x8 k1 = *(const f16x8*)&Ks[cur][SLOT(32 + ln, cd)];
            s0 = __builtin_amdgcn_mfma_f32_32x32x16_f16(k0, qf[kc], s0, 0, 0, 0);
            s1 = __builtin_amdgcn_mfma_f32_32x32x16_f16(k1, qf[kc], s1, 0, 0, 0);
        }

        // online softmax (base-2); lsum kept per half-lane, merged at end
        float mx = s0[0];
        #pragma unroll
        for (int r = 1; r < 16; ++r) mx = fmaxf(mx, s0[r]);
        #pragma unroll
        for (int r = 0; r < 16; ++r) mx = fmaxf(mx, s1[r]);
        mx = fmaxf(mx, __shfl_xor(mx, 32));
        if (__any(mx > m_st)) {            // wave-uniform: skip rescale when stale max holds
            float mnew = fmaxf(m_st, mx);
            float alpha = exp2f(m_st - mnew);
            m_st = mnew;
            lsum *= alpha;
            #pragma unroll
            for (int r = 0; r < 16; ++r) { acc0[r] *= alpha; acc1[r] *= alpha; }
        }
        float rsum = 0.f;
        #pragma unroll
        for (int r = 0; r < 16; ++r) { float p = exp2f(s0[r] - m_st); s0[r] = p; rsum += p; }
        #pragma unroll
        for (int r = 0; r < 16; ++r) { float p = exp2f(s1[r] - m_st); s1[r] = p; rsum += p; }
        lsum += rsum;

        // P -> per-wave LDS
        #pragma unroll
        for (int g = 0; g < 4; ++g) {
            uint2 w0;
            w0.x = pk2(s0[g * 4 + 0], s0[g * 4 + 1]);
            w0.y = pk2(s0[g * 4 + 2], s0[g * 4 + 3]);
            *(uint2*)&Ps[wave][(g * 32 + (ln ^ g)) * 8 + hi * 4] = w0;
            int g2 = 4 + g;
            uint2 w1;
            w1.x = pk2(s1[g * 4 + 0], s1[g * 4 + 1]);
            w1.y = pk2(s1[g * 4 + 2], s1[g * 4 + 3]);
            *(uint2*)&Ps[wave][(g2 * 32 + (ln ^ g2)) * 8 + hi * 4] = w1;
        }

        // O^T += V . P^T  (per-wave P; lgkmcnt orders write->read)
        #pragma unroll
        for (int kc = 0; kc < 4; ++kc) {
            int cd = kc * 2 + hi;
            f16x8 pf = *(const f16x8*)&Ps[wave][(cd * 32 + (ln ^ cd)) * 8];
            f16x8 v0 = *(const f16x8*)&Vs[cur][SLOT(ln, cd)];
            f16x8 v1 = *(const f16x8*)&Vs[cur][SLOT(32 + ln, cd)];
            acc0 = __builtin_amdgcn_mfma_f32_32x32x16_f16(v0, pf, acc0, 0, 0, 0);
            acc1 = __builtin_amdgcn_mfma_f32_32x32x16_f16(v1, pf, acc1, 0, 0, 0);
        }

        if (it < 15) {                     // stage next tile (buf free: all waves past barrier)
            #pragma unroll
            for (int j = 0; j < 2; ++j) {
                int row = urow + j * 32;
                *(uint4*)&Ks[cur ^ 1][SLOT(row, uci)] = kreg[j];
                *(uint4*)&Vs[cur ^ 1][SLOT(row, uci)] = vreg[j];
            }
        }
    }

    float l_tot = lsum + __shfl_xor(lsum, 32);
    unsigned short* Ow = Opart + (size_t)(sp * 8 + bh) * 64 * 4096;
    #pragma unroll
    for (int r = 0; r < 16; ++r) {
        int d0 = (r & 3) + 8 * (r >> 2) + 4 * hi;
        Ow[(size_t)d0 * 4096 + lq] = f2h(acc0[r]);
        Ow[(size_t)(32 + d0) * 4096 + lq] = f2h(acc1[r]);
    }
    if (hi == 0) {
        Mpart[(sp * 8 + bh) * 4096 + lq] = m_st;
        Lpart[(sp * 8 + bh) * 4096 + lq] = l_tot;
    }
}

// ---------------- K2b: per-(bh,l) combine scales -> f16x4 ----------------
__global__ __launch_bounds__(256) void scale_kernel(
    const float* __restrict__ Mp, const float* __restrict__ Lp,
    unsigned short* __restrict__ Scl)
{
    int t = blockIdx.x * 256 + threadIdx.x;   // bh*4096 + l
    float m[4], l[4];
    #pragma unroll
    for (int s = 0; s < 4; ++s) { m[s] = Mp[s * 32768 + t]; l[s] = Lp[s * 32768 + t]; }
    float mx = fmaxf(fmaxf(m[0], m[1]), fmaxf(m[2], m[3]));
    float a[4], den = 0.f;
    #pragma unroll
    for (int s = 0; s < 4; ++s) { a[s] = exp2f(m[s] - mx); den += a[s] * l[s]; }
    float inv = 1.0f / den;
    uint2 sc;
    sc.x = pk2(a[0] * inv, a[1] * inv);
    sc.y = pk2(a[2] * inv, a[3] * inv);
    *(uint2*)&Scl[t * 4] = sc;
}

// ---------------- K3: combine + fc + BN + PReLU ----------------
// Grid 512 = b(4) x ch(128). Block 256: wave -> (h-half, o-half); 16 rows x 64 o.
__global__ __launch_bounds__(256) void fc_kernel(
    const unsigned short* __restrict__ Opart, const unsigned short* __restrict__ Scl,
    const unsigned short* __restrict__ fcwh, const float* __restrict__ fc_b,
    const float* __restrict__ bn_g, const float* __restrict__ bn_b,
    const float* __restrict__ bn_m, const float* __restrict__ bn_v,
    const float* __restrict__ prelu_a, float* __restrict__ out)
{
    int blk = blockIdx.x;
    int b = blk >> 7, ch = blk & 127;
    int bh = b * 2 + (ch >> 6);
    int d = ch & 63;
    int tid = threadIdx.x;
    int wave = tid >> 6, lane = tid & 63;
    int c = lane & 15, qd = lane >> 4;
    int hhb = (wave >> 1) * 16;
    int nb = (wave & 1) * 64;
    int h_tok = hhb + c;

    size_t obase = (size_t)bh * 262144 + (size_t)d * 4096 + h_tok * 128;
    int sbase = (bh << 12) + h_tok * 128;

    f16x8 af[4];
    #pragma unroll
    for (int kc = 0; kc < 4; ++kc) {
        int w0 = kc * 32 + qd * 8;
        f16x8 ov[4];
        #pragma unroll
        for (int s = 0; s < 4; ++s)
            ov[s] = *(const f16x8*)&Opart[(size_t)s * 2097152 + obase + w0];
        #pragma unroll
        for (int j = 0; j < 8; ++j) {
            f16x4t sc = *(const f16x4t*)&Scl[(sbase + w0 + j) * 4];
            float v = (float)ov[0][j] * (float)sc[0] + (float)ov[1][j] * (float)sc[1]
                    + (float)ov[2][j] * (float)sc[2] + (float)ov[3][j] * (float)sc[3];
            af[kc][j] = (_Float16)v;
        }
    }

    f32x4 acc[4];
    #pragma unroll
    for (int nt = 0; nt < 4; ++nt) acc[nt] = (f32x4){0.f,0.f,0.f,0.f};
    #pragma unroll
    for (int kc = 0; kc < 4; ++kc) {
        #pragma unroll
        for (int nt = 0; nt < 4; ++nt) {
            int o = nb + nt * 16 + c;
            f16x8 bf = *(const f16x8*)&fcwh[o * 128 + kc * 32 + qd * 8];
            acc[nt] = __builtin_amdgcn_mfma_f32_16x16x32_f16(af[kc], bf, acc[nt], 0, 0, 0);
        }
    }

    float pa = prelu_a[0];
    float g  = bn_g[ch] * rsqrtf(bn_v[ch] + 1e-5f);
    float mn = bn_m[ch], bt = bn_b[ch];
    size_t rbase = ((size_t)(b * 128 + ch)) * 32;
    #pragma unroll
    for (int r = 0; r < 4; ++r) {
        size_t orow = rbase + hhb + qd * 4 + r;
        #pragma unroll
        for (int nt = 0; nt < 4; ++nt) {
            int o = nb + nt * 16 + c;
            float y = (acc[nt][r] + fc_b[o] - mn) * g + bt;
            y = y > 0.f ? y : pa * y;
            out[orow * 128 + o] = y;
        }
    }
}

extern "C" void kernel_launch(void* const* d_in, const int* in_sizes, int n_in,
                              void* d_out, int out_size, void* d_ws, size_t ws_size,
                              hipStream_t stream) {
    const float* x     = (const float*)d_in[0];
    const float* wq    = (const float*)d_in[1];
    const float* bq    = (const float*)d_in[2];
    const float* wk    = (const float*)d_in[3];
    const float* bk    = (const float*)d_in[4];
    const float* wv    = (const float*)d_in[5];
    const float* bv    = (const float*)d_in[6];
    const float* fcw_f = (const float*)d_in[7];
    const float* fcb   = (const float*)d_in[8];
    const float* bn_g  = (const float*)d_in[9];
    const float* bn_b  = (const float*)d_in[10];
    const float* bn_m  = (const float*)d_in[11];
    const float* bn_v  = (const float*)d_in[12];
    const float* pa    = (const float*)d_in[13];
    float* out = (float*)d_out;

    unsigned short* Wc    = (unsigned short*)d_ws;      // 49152
    unsigned short* fcwh  = Wc + 49152;                 // 16384
    unsigned short* Qp    = fcwh + 16384;               // 2097152 each
    unsigned short* Kp    = Qp + 2097152;
    unsigned short* Vp    = Kp + 2097152;
    unsigned short* Opart = Vp + 2097152;               // 4*8*64*4096 = 8388608
    float* Mpart = (float*)(Opart + 8388608);           // 4*8*4096 = 131072 floats
    float* Lpart = Mpart + 131072;                      // 131072 floats  (was 32768: BUG)
    unsigned short* Scl = (unsigned short*)(Lpart + 131072);  // 131072 * 4 f16

    hipLaunchKernelGGL(cvt_kernel,   dim3(256),  dim3(256), 0, stream,
                       wq, wk, wv, fcw_f, Wc, fcwh);
    hipLaunchKernelGGL(qkv_kernel,   dim3(1536), dim3(256), 0, stream,
                       x, Wc, bq, bk, bv, Qp, Kp, Vp);
    hipLaunchKernelGGL(attn_kernel,  dim3(1024), dim3(256), 0, stream,
                       Qp, Kp, Vp, Opart, Mpart, Lpart);
    hipLaunchKernelGGL(scale_kernel, dim3(128),  dim3(256), 0, stream,
                       Mpart, Lpart, Scl);
    hipLaunchKernelGGL(fc_kernel,    dim3(512),  dim3(256), 0, stream,
                       Opart, Scl, fcwh, fcb, bn_g, bn_b, bn_m, bn_v, pa, out);
}

// Round 9
// 177.133 us; speedup vs baseline: 1.2226x; 1.0079x over previous
//
#include <hip/hip_runtime.h>

typedef _Float16 f16x8 __attribute__((ext_vector_type(8)));
typedef _Float16 f16x4t __attribute__((ext_vector_type(4)));
typedef __fp16 h16x2 __attribute__((ext_vector_type(2)));
typedef float f32x4 __attribute__((ext_vector_type(4)));
typedef float f32x16 __attribute__((ext_vector_type(16)));

#define L_SZ 4096

__device__ __forceinline__ unsigned short f2h(float f) {
    _Float16 h = (_Float16)f;
    return __builtin_bit_cast(unsigned short, h);
}
__device__ __forceinline__ unsigned int pk2(float a, float b) {
    h16x2 p = __builtin_amdgcn_cvt_pkrtz(a, b);
    return __builtin_bit_cast(unsigned int, p);
}

// K/V LDS slot: 64-row x 8-chunk (16B) tiles, chunk-major, XOR perm.
#define SLOT(row, ci) ((((ci) * 64) + ((row) & 32) + (((row) & 31) ^ (ci))) * 8)

// ---------------- K0: convert weights fp32 -> f16 ----------------
__global__ __launch_bounds__(256) void cvt_kernel(
    const float* __restrict__ wq, const float* __restrict__ wk,
    const float* __restrict__ wv, const float* __restrict__ fcw_f,
    unsigned short* __restrict__ Wc, unsigned short* __restrict__ fcwh)
{
    int t = blockIdx.x * 256 + threadIdx.x;   // 65536
    if (t < 16384)       Wc[t]          = f2h(wq[t]);
    else if (t < 32768)  Wc[t]          = f2h(wk[t - 16384]);
    else if (t < 49152)  Wc[t]          = f2h(wv[t - 32768]);
    else                 fcwh[t - 49152] = f2h(fcw_f[t - 49152]);
}

// ---------------- K1: QKV projection (round-8 verbatim) -------------------
__global__ __launch_bounds__(256) void qkv_kernel(
    const float* __restrict__ x, const unsigned short* __restrict__ Wc,
    const float* __restrict__ bq, const float* __restrict__ bk, const float* __restrict__ bv,
    unsigned short* __restrict__ Qp, unsigned short* __restrict__ Kp,
    unsigned short* __restrict__ Vp)
{
    int blk = blockIdx.x;
    int proj = blk >> 9;               // 0=Q 1=K 2=V
    int rem = blk & 511;
    int bidx = rem >> 7;
    int l0 = (rem & 127) * 32;
    int tid = threadIdx.x;
    int wave = tid >> 6, lane = tid & 63;
    int c = lane & 15, qd = lane >> 4;

    const float* bia = (proj == 0) ? bq : (proj == 1 ? bk : bv);

    __shared__ __align__(16) unsigned short Sh[5120];  // Xs 4096 / Qt 4352 / Vt 5120

    {
        int i  = tid >> 1;
        int lh = (tid & 1) * 16;
        const float* xs = &x[((size_t)bidx * 128 + i) * L_SZ + l0 + lh];
        float4 v0 = *(const float4*)xs;
        float4 v1 = *(const float4*)(xs + 4);
        float4 v2 = *(const float4*)(xs + 8);
        float4 v3 = *(const float4*)(xs + 12);
        float vv[16] = {v0.x,v0.y,v0.z,v0.w, v1.x,v1.y,v1.z,v1.w,
                        v2.x,v2.y,v2.z,v2.w, v3.x,v3.y,v3.z,v3.w};
        int ci = i >> 3, ij = i & 7;
        #pragma unroll
        for (int t = 0; t < 16; ++t) {
            int l = lh + t;
            Sh[l * 128 + ((ci ^ (l & 15)) * 8) + ij] = f2h(vv[t]);
        }
    }
    __syncthreads();

    f16x8 af[2][4];
    #pragma unroll
    for (int lt2 = 0; lt2 < 2; ++lt2)
        #pragma unroll
        for (int kc = 0; kc < 4; ++kc)
            af[lt2][kc] = *(const f16x8*)&Sh[(lt2 * 16 + c) * 128 + (((kc * 4 + qd) ^ c) * 8)];
    __syncthreads();

    f32x4 acc[2][2];
    #pragma unroll
    for (int lt2 = 0; lt2 < 2; ++lt2)
        #pragma unroll
        for (int nt = 0; nt < 2; ++nt) acc[lt2][nt] = (f32x4){0.f,0.f,0.f,0.f};

    const unsigned short* Wp = Wc + proj * 16384;
    #pragma unroll
    for (int kc = 0; kc < 4; ++kc) {
        #pragma unroll
        for (int nt = 0; nt < 2; ++nt) {
            int o = wave * 32 + nt * 16 + c;
            f16x8 bf = *(const f16x8*)&Wp[o * 128 + kc * 32 + qd * 8];
            acc[0][nt] = __builtin_amdgcn_mfma_f32_16x16x32_f16(af[0][kc], bf, acc[0][nt], 0, 0, 0);
            acc[1][nt] = __builtin_amdgcn_mfma_f32_16x16x32_f16(af[1][kc], bf, acc[1][nt], 0, 0, 0);
        }
    }

    const float s_q = 0.18033688011f;  // log2(e)/8
    if (proj < 2) {
        #pragma unroll
        for (int lt2 = 0; lt2 < 2; ++lt2)
            #pragma unroll
            for (int nt = 0; nt < 2; ++nt) {
                int o = wave * 32 + nt * 16 + c;
                float bo = bia[o];
                #pragma unroll
                for (int r = 0; r < 4; ++r) {
                    float val = acc[lt2][nt][r] + bo;
                    if (proj == 0) val *= s_q;
                    Sh[(lt2 * 16 + qd * 4 + r) * 136 + o] = f2h(val);
                }
            }
        __syncthreads();
        unsigned short* dstp = (proj == 0) ? Qp : Kp;
        int l = tid >> 3, cp = tid & 7;
        int h = cp >> 2;
        uint4 q0 = *(const uint4*)&Sh[l * 136 + cp * 16];
        uint4 q1 = *(const uint4*)&Sh[l * 136 + cp * 16 + 8];
        unsigned short* d0 = &dstp[((size_t)(bidx * 2 + h) * L_SZ + l0 + l) * 64 + ((cp * 16) & 63)];
        *(uint4*)d0 = q0;
        *(uint4*)(d0 + 8) = q1;
    } else {
        #pragma unroll
        for (int lt2 = 0; lt2 < 2; ++lt2)
            #pragma unroll
            for (int nt = 0; nt < 2; ++nt) {
                int o = wave * 32 + nt * 16 + c;
                float bo = bia[o];
                #pragma unroll
                for (int r = 0; r < 4; ++r)
                    Sh[o * 40 + lt2 * 16 + qd * 4 + r] = f2h(acc[lt2][nt][r] + bo);
            }
        __syncthreads();
        int row = tid >> 1, half = (tid & 1) * 16;
        uint4 a0 = *(const uint4*)&Sh[row * 40 + half];
        uint4 a1 = *(const uint4*)&Sh[row * 40 + half + 8];
        unsigned short* d0 = &Vp[((size_t)(bidx * 128 + row)) * L_SZ + l0 + half];
        *(uint4*)d0 = a0;
        *(uint4*)(d0 + 8) = a1;
    }
}

// ---------------- K2: flash attention (register-P, tree softmax, 32KB) ----
// Grid 1024 = sp(4) x bh(8) x ltile(32). 4 waves x 32 q-rows.
// Opart f16 [sp][bh][d][l] unnormalized; Mpart/Lpart f32 [sp][bh][l].
__global__ __launch_bounds__(256, 3) void attn_kernel(
    const unsigned short* __restrict__ Qp, const unsigned short* __restrict__ Kp,
    const unsigned short* __restrict__ Vp,
    unsigned short* __restrict__ Opart, float* __restrict__ Mpart, float* __restrict__ Lpart)
{
    int blk = blockIdx.x;
    int lt = blk & 31;
    int bh = (blk >> 5) & 7;
    int sp = blk >> 8;
    int l0 = lt * 128;
    int tid = threadIdx.x;
    int wave = tid >> 6, lane = tid & 63;
    int ln = lane & 31, hi = lane >> 5;
    int b = bh >> 1, h = bh & 1;

    __shared__ __align__(16) unsigned short Ks[2][4096];
    __shared__ __align__(16) unsigned short Vs[2][4096];

    const unsigned short* Qb = Qp + (size_t)bh * L_SZ * 64;
    const unsigned short* Kb = Kp + (size_t)bh * L_SZ * 64;
    const unsigned short* Vb = Vp + ((size_t)b * 128 + h * 64) * L_SZ;

    int lq = l0 + wave * 32 + ln;
    f16x8 qf[4];   // B-operand: n = q-row ln, k chunks
    #pragma unroll
    for (int kc = 0; kc < 4; ++kc)
        qf[kc] = *(const f16x8*)&Qb[(size_t)lq * 64 + kc * 16 + hi * 8];

    float m_st = -1e30f, lsum = 0.f;
    f32x16 acc0 = {}, acc1 = {};

    int urow = tid >> 3, uci = tid & 7;
    int mglob = sp * 1024;

    uint4 kreg[2], vreg[2];
    #pragma unroll
    for (int j = 0; j < 2; ++j) {
        int row = urow + j * 32;
        kreg[j] = *(const uint4*)&Kb[(size_t)(mglob + row) * 64 + uci * 8];
        vreg[j] = *(const uint4*)&Vb[(size_t)row * L_SZ + mglob + uci * 8];
    }
    #pragma unroll
    for (int j = 0; j < 2; ++j) {
        int row = urow + j * 32;
        *(uint4*)&Ks[0][SLOT(row, uci)] = kreg[j];
        *(uint4*)&Vs[0][SLOT(row, uci)] = vreg[j];
    }

    for (int it = 0; it < 16; ++it) {
        int cur = it & 1;
        __syncthreads();                   // buf[cur] staged; buf[cur^1] reads done
        if (it < 15) {                     // prefetch next tile to regs
            int m0 = mglob + (it + 1) * 64;
            #pragma unroll
            for (int j = 0; j < 2; ++j) {
                int row = urow + j * 32;
                kreg[j] = *(const uint4*)&Kb[(size_t)(m0 + row) * 64 + uci * 8];
                vreg[j] = *(const uint4*)&Vb[(size_t)row * L_SZ + m0 + uci * 8];
            }
        }

        // S^T = K . Q^T
        f32x16 s0 = {}, s1 = {};
        #pragma unroll
        for (int kc = 0; kc < 4; ++kc) {
            int cd = kc * 2 + hi;
            f16x8 k0 = *(const f16x8*)&Ks[cur][SLOT(ln, cd)];
            f16x8 k1 = *(const f16x8*)&Ks[cur][SLOT(32 + ln, cd)];
            s0 = __builtin_amdgcn_mfma_f32_32x32x16_f16(k0, qf[kc], s0, 0, 0, 0);
            s1 = __builtin_amdgcn_mfma_f32_32x32x16_f16(k1, qf[kc], s1, 0, 0, 0);
        }

        // --- online softmax, tree reductions (depth ~5, not 63) ---
        float t[16];
        #pragma unroll
        for (int r = 0; r < 16; ++r) t[r] = fmaxf(s0[r], s1[r]);
        #pragma unroll
        for (int r = 0; r < 8; ++r) t[r] = fmaxf(t[r], t[r + 8]);
        #pragma unroll
        for (int r = 0; r < 4; ++r) t[r] = fmaxf(t[r], t[r + 4]);
        float mx = fmaxf(fmaxf(t[0], t[1]), fmaxf(t[2], t[3]));
        mx = fmaxf(mx, __shfl_xor(mx, 32));
        if (__any(mx > m_st)) {            // wave-uniform skip when stale max holds
            float mnew = fmaxf(m_st, mx);
            float alpha = exp2f(m_st - mnew);
            m_st = mnew;
            lsum *= alpha;
            #pragma unroll
            for (int r = 0; r < 16; ++r) { acc0[r] *= alpha; acc1[r] *= alpha; }
        }
        #pragma unroll
        for (int r = 0; r < 16; ++r) { s0[r] = exp2f(s0[r] - m_st); s1[r] = exp2f(s1[r] - m_st); }
        float u[16];
        #pragma unroll
        for (int r = 0; r < 16; ++r) u[r] = s0[r] + s1[r];
        #pragma unroll
        for (int r = 0; r < 8; ++r) u[r] += u[r + 8];
        #pragma unroll
        for (int r = 0; r < 4; ++r) u[r] += u[r + 4];
        lsum += (u[0] + u[1]) + (u[2] + u[3]);

        // --- P: register transpose C-layout -> B-operand layout -----------
        // lane(ln,hi) holds m = (r&3)+8*(r>>2)+4*hi. B-op needs m = mb*16+hi*8+jj.
        // Exchange packed halves across hi via shfl_xor(32).
        uint4 pfrag[4];
        #pragma unroll
        for (int g = 0; g < 4; ++g) {
            const float* sv = (g < 2) ? (const float*)&s0 : (const float*)&s1;
            int br = (g & 1) * 8;
            unsigned int pax = pk2(sv[br + 0], sv[br + 1]);
            unsigned int pay = pk2(sv[br + 2], sv[br + 3]);
            unsigned int pbx = pk2(sv[br + 4], sv[br + 5]);
            unsigned int pby = pk2(sv[br + 6], sv[br + 7]);
            unsigned int sx = hi ? pax : pbx;
            unsigned int sy = hi ? pay : pby;
            unsigned int rx = __shfl_xor(sx, 32);
            unsigned int ry = __shfl_xor(sy, 32);
            uint4 f;
            f.x = hi ? rx : pax;
            f.y = hi ? ry : pay;
            f.z = hi ? pbx : rx;
            f.w = hi ? pby : ry;
            pfrag[g] = f;
        }

        // O^T += V . P^T (P from registers)
        #pragma unroll
        for (int mb = 0; mb < 4; ++mb) {
            int cd = mb * 2 + hi;
            f16x8 pf = __builtin_bit_cast(f16x8, pfrag[mb]);
            f16x8 v0 = *(const f16x8*)&Vs[cur][SLOT(ln, cd)];
            f16x8 v1 = *(const f16x8*)&Vs[cur][SLOT(32 + ln, cd)];
            acc0 = __builtin_amdgcn_mfma_f32_32x32x16_f16(v0, pf, acc0, 0, 0, 0);
            acc1 = __builtin_amdgcn_mfma_f32_32x32x16_f16(v1, pf, acc1, 0, 0, 0);
        }

        if (it < 15) {                     // stage next tile into other buffer
            #pragma unroll
            for (int j = 0; j < 2; ++j) {
                int row = urow + j * 32;
                *(uint4*)&Ks[cur ^ 1][SLOT(row, uci)] = kreg[j];
                *(uint4*)&Vs[cur ^ 1][SLOT(row, uci)] = vreg[j];
            }
        }
    }

    float l_tot = lsum + __shfl_xor(lsum, 32);
    unsigned short* Ow = Opart + (size_t)(sp * 8 + bh) * 64 * 4096;
    #pragma unroll
    for (int r = 0; r < 16; ++r) {
        int d0 = (r & 3) + 8 * (r >> 2) + 4 * hi;
        Ow[(size_t)d0 * 4096 + lq] = f2h(acc0[r]);
        Ow[(size_t)(32 + d0) * 4096 + lq] = f2h(acc1[r]);
    }
    if (hi == 0) {
        Mpart[(sp * 8 + bh) * 4096 + lq] = m_st;
        Lpart[(sp * 8 + bh) * 4096 + lq] = l_tot;
    }
}

// ---------------- K2b: per-(bh,l) combine scales -> f16x4 ----------------
__global__ __launch_bounds__(256) void scale_kernel(
    const float* __restrict__ Mp, const float* __restrict__ Lp,
    unsigned short* __restrict__ Scl)
{
    int t = blockIdx.x * 256 + threadIdx.x;   // bh*4096 + l
    float m[4], l[4];
    #pragma unroll
    for (int s = 0; s < 4; ++s) { m[s] = Mp[s * 32768 + t]; l[s] = Lp[s * 32768 + t]; }
    float mx = fmaxf(fmaxf(m[0], m[1]), fmaxf(m[2], m[3]));
    float a[4], den = 0.f;
    #pragma unroll
    for (int s = 0; s < 4; ++s) { a[s] = exp2f(m[s] - mx); den += a[s] * l[s]; }
    float inv = 1.0f / den;
    uint2 sc;
    sc.x = pk2(a[0] * inv, a[1] * inv);
    sc.y = pk2(a[2] * inv, a[3] * inv);
    *(uint2*)&Scl[t * 4] = sc;
}

// ---------------- K3: combine + fc + BN + PReLU (round-8 verbatim) --------
__global__ __launch_bounds__(256) void fc_kernel(
    const unsigned short* __restrict__ Opart, const unsigned short* __restrict__ Scl,
    const unsigned short* __restrict__ fcwh, const float* __restrict__ fc_b,
    const float* __restrict__ bn_g, const float* __restrict__ bn_b,
    const float* __restrict__ bn_m, const float* __restrict__ bn_v,
    const float* __restrict__ prelu_a, float* __restrict__ out)
{
    int blk = blockIdx.x;
    int b = blk >> 7, ch = blk & 127;
    int bh = b * 2 + (ch >> 6);
    int d = ch & 63;
    int tid = threadIdx.x;
    int wave = tid >> 6, lane = tid & 63;
    int c = lane & 15, qd = lane >> 4;
    int hhb = (wave >> 1) * 16;
    int nb = (wave & 1) * 64;
    int h_tok = hhb + c;

    size_t obase = (size_t)bh * 262144 + (size_t)d * 4096 + h_tok * 128;
    int sbase = (bh << 12) + h_tok * 128;

    f16x8 af[4];
    #pragma unroll
    for (int kc = 0; kc < 4; ++kc) {
        int w0 = kc * 32 + qd * 8;
        f16x8 ov[4];
        #pragma unroll
        for (int s = 0; s < 4; ++s)
            ov[s] = *(const f16x8*)&Opart[(size_t)s * 2097152 + obase + w0];
        #pragma unroll
        for (int j = 0; j < 8; ++j) {
            f16x4t sc = *(const f16x4t*)&Scl[(sbase + w0 + j) * 4];
            float v = (float)ov[0][j] * (float)sc[0] + (float)ov[1][j] * (float)sc[1]
                    + (float)ov[2][j] * (float)sc[2] + (float)ov[3][j] * (float)sc[3];
            af[kc][j] = (_Float16)v;
        }
    }

    f32x4 acc[4];
    #pragma unroll
    for (int nt = 0; nt < 4; ++nt) acc[nt] = (f32x4){0.f,0.f,0.f,0.f};
    #pragma unroll
    for (int kc = 0; kc < 4; ++kc) {
        #pragma unroll
        for (int nt = 0; nt < 4; ++nt) {
            int o = nb + nt * 16 + c;
            f16x8 bf = *(const f16x8*)&fcwh[o * 128 + kc * 32 + qd * 8];
            acc[nt] = __builtin_amdgcn_mfma_f32_16x16x32_f16(af[kc], bf, acc[nt], 0, 0, 0);
        }
    }

    float pa = prelu_a[0];
    float g  = bn_g[ch] * rsqrtf(bn_v[ch] + 1e-5f);
    float mn = bn_m[ch], bt = bn_b[ch];
    size_t rbase = ((size_t)(b * 128 + ch)) * 32;
    #pragma unroll
    for (int r = 0; r < 4; ++r) {
        size_t orow = rbase + hhb + qd * 4 + r;
        #pragma unroll
        for (int nt = 0; nt < 4; ++nt) {
            int o = nb + nt * 16 + c;
            float y = (acc[nt][r] + fc_b[o] - mn) * g + bt;
            y = y > 0.f ? y : pa * y;
            out[orow * 128 + o] = y;
        }
    }
}

extern "C" void kernel_launch(void* const* d_in, const int* in_sizes, int n_in,
                              void* d_out, int out_size, void* d_ws, size_t ws_size,
                              hipStream_t stream) {
    const float* x     = (const float*)d_in[0];
    const float* wq    = (const float*)d_in[1];
    const float* bq    = (const float*)d_in[2];
    const float* wk    = (const float*)d_in[3];
    const float* bk    = (const float*)d_in[4];
    const float* wv    = (const float*)d_in[5];
    const float* bv    = (const float*)d_in[6];
    const float* fcw_f = (const float*)d_in[7];
    const float* fcb   = (const float*)d_in[8];
    const float* bn_g  = (const float*)d_in[9];
    const float* bn_b  = (const float*)d_in[10];
    const float* bn_m  = (const float*)d_in[11];
    const float* bn_v  = (const float*)d_in[12];
    const float* pa    = (const float*)d_in[13];
    float* out = (float*)d_out;

    unsigned short* Wc    = (unsigned short*)d_ws;      // 49152
    unsigned short* fcwh  = Wc + 49152;                 // 16384
    unsigned short* Qp    = fcwh + 16384;               // 2097152 each
    unsigned short* Kp    = Qp + 2097152;
    unsigned short* Vp    = Kp + 2097152;
    unsigned short* Opart = Vp + 2097152;               // 4*8*64*4096 = 8388608
    float* Mpart = (float*)(Opart + 8388608);           // 131072 floats
    float* Lpart = Mpart + 131072;                      // 131072 floats
    unsigned short* Scl = (unsigned short*)(Lpart + 131072);  // 131072 * 4 f16

    hipLaunchKernelGGL(cvt_kernel,   dim3(256),  dim3(256), 0, stream,
                       wq, wk, wv, fcw_f, Wc, fcwh);
    hipLaunchKernelGGL(qkv_kernel,   dim3(1536), dim3(256), 0, stream,
                       x, Wc, bq, bk, bv, Qp, Kp, Vp);
    hipLaunchKernelGGL(attn_kernel,  dim3(1024), dim3(256), 0, stream,
                       Qp, Kp, Vp, Opart, Mpart, Lpart);
    hipLaunchKernelGGL(scale_kernel, dim3(128),  dim3(256), 0, stream,
                       Mpart, Lpart, Scl);
    hipLaunchKernelGGL(fc_kernel,    dim3(512),  dim3(256), 0, stream,
                       Opart, Scl, fcwh, fcb, bn_g, bn_b, bn_m, bn_v, pa, out);
}